// Round 2
// baseline (1023.769 us; speedup 1.0000x reference)
//
#include <hip/hip_runtime.h>
#include <hip/hip_bf16.h>

// QLSTM: T=512, B=256, D=128, H=256, P=128, GAMMA=1
// Phase 1 (MFMA GEMM): sx[r,p] = ||x_r||^2 + ||px_p||^2 - 2 x_r.px_p  (full Sx, f16, 32MB ws)
// Phase 2 (sequential, 1 WG of 1024 per batch row):
//   Sh via 8 lanes/prototype (32 dims each) with fused |hx|^2 (sq=fdot2(u,u)) so no
//   cross-wave hnorm reduce; k=exp(-(Sx+Sh)); gates: 1 gate-output/thread, fp16
//   weights (64 VGPRs) + b128 LDS broadcast of k.

#define TT 512
#define BB 256
#define DD 128
#define HH 256
#define PP 128
#define DHH 384

typedef _Float16 h2 __attribute__((ext_vector_type(2)));
typedef _Float16 h8 __attribute__((ext_vector_type(8)));
typedef float f4v __attribute__((ext_vector_type(4)));

union F4H { float4 f; h2 h[4]; };

__device__ __forceinline__ float fdot2f(h2 a, h2 b, float c) {
#if __has_builtin(__builtin_amdgcn_fdot2)
  return __builtin_amdgcn_fdot2(a, b, c, false);
#else
  return c + (float)a.x * (float)b.x + (float)a.y * (float)b.y;
#endif
}

__device__ __forceinline__ float sigm_f(float x) { return 1.f / (1.f + __expf(-x)); }
__device__ __forceinline__ float tanh_f(float x) { return 1.f - 2.f / (1.f + __expf(2.f * x)); }

// ---------------- Phase 1: Sx via MFMA f16 ----------------
// 512 WGs x 256 threads; each WG does 256 rows (4 tiles of 64), all 128 p.
// LDS rows padded to 136 halves (272B) to spread banks.
__global__ __launch_bounds__(256, 2) void sx_kernel(const float* __restrict__ x,
                                                    const float* __restrict__ proto,
                                                    _Float16* __restrict__ sx) {
  __shared__ __align__(16) _Float16 qlds[PP * 136];   // -2*proto_x, f16
  __shared__ __align__(16) _Float16 xlds[64 * 136];   // x tile, f16
  __shared__ float pnlds[PP];
  __shared__ float xnlds[64];

  const int t = threadIdx.x;
  const int lane = t & 63;
  const int wv = t >> 6;          // wave 0..3 -> m-tile
  const int col = lane & 15;
  const int quad = lane >> 4;
  const int r0 = blockIdx.x * 256;

  // ---- stage q = -2*proto_x (f16) + pnorm ----
  {
    const int p = t >> 1;
    const int hh = t & 1;
    const float* src = proto + p * DHH + hh * 64;
    _Float16* dst = qlds + p * 136 + hh * 64;
    float pn = 0.f;
#pragma unroll
    for (int i = 0; i < 8; ++i) {
      float4 a = *(const float4*)(src + i * 8);
      float4 b = *(const float4*)(src + i * 8 + 4);
      pn = fmaf(a.x, a.x, fmaf(a.y, a.y, fmaf(a.z, a.z, fmaf(a.w, a.w, pn))));
      pn = fmaf(b.x, b.x, fmaf(b.y, b.y, fmaf(b.z, b.z, fmaf(b.w, b.w, pn))));
      h8 v;
      v[0] = (_Float16)(-2.f * a.x); v[1] = (_Float16)(-2.f * a.y);
      v[2] = (_Float16)(-2.f * a.z); v[3] = (_Float16)(-2.f * a.w);
      v[4] = (_Float16)(-2.f * b.x); v[5] = (_Float16)(-2.f * b.y);
      v[6] = (_Float16)(-2.f * b.z); v[7] = (_Float16)(-2.f * b.w);
      *(h8*)(dst + i * 8) = v;
    }
    pn += __shfl_xor(pn, 1);
    if (hh == 0) pnlds[p] = pn;
  }

  // ---- stage x tile 0 ----
  {
    const int m = t >> 2;
    const int q4 = t & 3;
    const float* xs = x + ((size_t)(r0 + m)) * DD + q4 * 32;
    _Float16* xd = xlds + m * 136 + q4 * 32;
    float xn = 0.f;
#pragma unroll
    for (int i = 0; i < 4; ++i) {
      float4 a = *(const float4*)(xs + i * 8);
      float4 b = *(const float4*)(xs + i * 8 + 4);
      xn = fmaf(a.x, a.x, fmaf(a.y, a.y, fmaf(a.z, a.z, fmaf(a.w, a.w, xn))));
      xn = fmaf(b.x, b.x, fmaf(b.y, b.y, fmaf(b.z, b.z, fmaf(b.w, b.w, xn))));
      h8 v;
      v[0] = (_Float16)a.x; v[1] = (_Float16)a.y; v[2] = (_Float16)a.z; v[3] = (_Float16)a.w;
      v[4] = (_Float16)b.x; v[5] = (_Float16)b.y; v[6] = (_Float16)b.z; v[7] = (_Float16)b.w;
      *(h8*)(xd + i * 8) = v;
    }
    xn += __shfl_xor(xn, 1);
    xn += __shfl_xor(xn, 2);
    if (q4 == 0) xnlds[m] = xn;
  }
  __syncthreads();

  float pn8[8];
#pragma unroll
  for (int nt = 0; nt < 8; ++nt) pn8[nt] = pnlds[nt * 16 + col];

  for (int tile = 0; tile < 4; ++tile) {
    // ---- compute: wave wv owns 16 rows m0 = wv*16 of this tile ----
    h8 af[4];
#pragma unroll
    for (int kc = 0; kc < 4; ++kc)
      af[kc] = *(const h8*)(xlds + (wv * 16 + col) * 136 + kc * 32 + quad * 8);
    float xnq[4];
#pragma unroll
    for (int r = 0; r < 4; ++r) xnq[r] = xnlds[wv * 16 + quad * 4 + r];

#pragma unroll
    for (int nt = 0; nt < 8; ++nt) {
      f4v acc;
      acc[0] = pn8[nt]; acc[1] = pn8[nt]; acc[2] = pn8[nt]; acc[3] = pn8[nt];
#pragma unroll
      for (int kc = 0; kc < 4; ++kc) {
        h8 bf = *(const h8*)(qlds + (nt * 16 + col) * 136 + kc * 32 + quad * 8);
        acc = __builtin_amdgcn_mfma_f32_16x16x32_f16(af[kc], bf, acc, 0, 0, 0);
      }
#pragma unroll
      for (int r = 0; r < 4; ++r) {
        const int row = r0 + tile * 64 + wv * 16 + quad * 4 + r;
        sx[(size_t)row * PP + nt * 16 + col] = (_Float16)(acc[r] + xnq[r]);
      }
    }

    // ---- stage next x tile ----
    if (tile < 3) {
      __syncthreads();  // compute done before xlds overwrite
      const int m = t >> 2;
      const int q4 = t & 3;
      const float* xs = x + ((size_t)(r0 + (tile + 1) * 64 + m)) * DD + q4 * 32;
      _Float16* xd = xlds + m * 136 + q4 * 32;
      float xn = 0.f;
#pragma unroll
      for (int i = 0; i < 4; ++i) {
        float4 a = *(const float4*)(xs + i * 8);
        float4 b = *(const float4*)(xs + i * 8 + 4);
        xn = fmaf(a.x, a.x, fmaf(a.y, a.y, fmaf(a.z, a.z, fmaf(a.w, a.w, xn))));
        xn = fmaf(b.x, b.x, fmaf(b.y, b.y, fmaf(b.z, b.z, fmaf(b.w, b.w, xn))));
        h8 v;
        v[0] = (_Float16)a.x; v[1] = (_Float16)a.y; v[2] = (_Float16)a.z; v[3] = (_Float16)a.w;
        v[4] = (_Float16)b.x; v[5] = (_Float16)b.y; v[6] = (_Float16)b.z; v[7] = (_Float16)b.w;
        *(h8*)(xd + i * 8) = v;
      }
      xn += __shfl_xor(xn, 1);
      xn += __shfl_xor(xn, 2);
      if (q4 == 0) xnlds[m] = xn;
      __syncthreads();
    }
  }
}

// ---------------- Phase 2: sequential recurrence ----------------
// grid 256 x 1024 threads (16 waves/CU, VGPR<=128, no spills).
// Sh: 8 threads per prototype (cc=t&7 covers 32 dims each); dot AND |hx|^2
//   both accumulated via fdot2 and reduced in the same 3-stage shuffle.
// Gates: thread t computes gate sel=t>>8 (f,i,g,o) for h=t&255; 64 fdot2,
//   weights in 64 VGPRs, k broadcast from LDS via b128 (uniform addr = free).
// hx in LDS as 4 chunks of 64 halves padded to stride 72 (conflict-free b128).
__global__ __launch_bounds__(1024, 4) void rec_kernel(
    const _Float16* __restrict__ sx, const float* __restrict__ proto,
    const float* __restrict__ Wf, const float* __restrict__ bfv,
    const float* __restrict__ Wi, const float* __restrict__ biv,
    const float* __restrict__ Wg, const float* __restrict__ bgv,
    const float* __restrict__ Wo, const float* __restrict__ bov,
    float* __restrict__ out) {
  const int b = blockIdx.x;
  const int t = threadIdx.x;
  const int h = t & (HH - 1);
  const int sel = t >> 8;  // 0:f 1:i 2:g 3:o  (wave-uniform)

  const float* Wsel = (sel == 0) ? Wf : (sel == 1) ? Wi : (sel == 2) ? Wg : Wo;
  const float* bsel = (sel == 0) ? bfv : (sel == 1) ? biv : (sel == 2) ? bgv : bov;
  const float bias = bsel[h];

  // one gate row of weights, fp16: 64 VGPRs
  h2 w[PP / 2];
#pragma unroll
  for (int j = 0; j < PP / 2; ++j) {
    float2 a = *(const float2*)(Wsel + h * PP + 2 * j);
    h2 u; u.x = (_Float16)a.x; u.y = (_Float16)a.y; w[j] = u;
  }

  // prototype h-part: 8 lanes per proto, 32 dims each -> 16 h2 regs
  const int p = t >> 3;
  const int cc = t & 7;
  h2 ph[16];
  float pnorm = 0.f;
#pragma unroll
  for (int j = 0; j < 16; ++j) {
    float2 a = *(const float2*)(proto + p * DHH + DD + cc * 32 + 2 * j);
    pnorm = fmaf(a.x, a.x, pnorm);
    pnorm = fmaf(a.y, a.y, pnorm);
    h2 u; u.x = (_Float16)(-2.f * a.x); u.y = (_Float16)(-2.f * a.y); ph[j] = u;
  }
  pnorm += __shfl_xor(pnorm, 1);
  pnorm += __shfl_xor(pnorm, 2);
  pnorm += __shfl_xor(pnorm, 4);

  // hx chunks: chunk c holds dims [c*64, c*64+64) at halves [c*72, c*72+64)
  __shared__ __align__(16) _Float16 hx2[4 * 72];
  __shared__ __align__(16) _Float16 kh2[PP];
  __shared__ float gates[4][HH];

  if (t < HH) hx2[(h >> 6) * 72 + (h & 63)] = (_Float16)0.f;
  float cx = 0.f;
  float hxr = 0.f;
  __syncthreads();

  float sx_next = (float)sx[(size_t)b * PP + p];

  const _Float16* hxc = hx2 + (cc >> 1) * 72 + (cc & 1) * 32;

  for (int step = 0; step < TT; ++step) {
    // ---- Sh + |hx|^2 + k ----
    float dA = 0.f, dB = 0.f, sA = 0.f, sB = 0.f;
#pragma unroll
    for (int j4 = 0; j4 < 4; ++j4) {
      F4H u; u.f = *(const float4*)(hxc + j4 * 8);
      dA = fdot2f(u.h[0], ph[4 * j4 + 0], dA);
      sA = fdot2f(u.h[0], u.h[0], sA);
      dB = fdot2f(u.h[1], ph[4 * j4 + 1], dB);
      sB = fdot2f(u.h[1], u.h[1], sB);
      dA = fdot2f(u.h[2], ph[4 * j4 + 2], dA);
      sA = fdot2f(u.h[2], u.h[2], sA);
      dB = fdot2f(u.h[3], ph[4 * j4 + 3], dB);
      sB = fdot2f(u.h[3], u.h[3], sB);
    }
    float dot = dA + dB;
    float sq = sA + sB;
    dot += __shfl_xor(dot, 1); sq += __shfl_xor(sq, 1);
    dot += __shfl_xor(dot, 2); sq += __shfl_xor(sq, 2);
    dot += __shfl_xor(dot, 4); sq += __shfl_xor(sq, 4);

    const float sx_cur = sx_next;
    const int nst = (step + 1 < TT) ? (step + 1) : (TT - 1);
    sx_next = (float)sx[((size_t)nst * BB + b) * PP + p];

    const float d2 = sq + dot + pnorm + sx_cur;
    const float kk = __expf(-d2);
    if (cc == 0) kh2[p] = (_Float16)kk;
    __syncthreads();  // k ready

    // ---- gate: 1 output/thread, b128 k broadcast, 4 acc chains ----
    float a0 = bias, a1 = 0.f, a2 = 0.f, a3 = 0.f;
#pragma unroll
    for (int j4 = 0; j4 < 16; ++j4) {
      F4H u; u.f = *(const float4*)(kh2 + j4 * 8);
      a0 = fdot2f(u.h[0], w[4 * j4 + 0], a0);
      a1 = fdot2f(u.h[1], w[4 * j4 + 1], a1);
      a2 = fdot2f(u.h[2], w[4 * j4 + 2], a2);
      a3 = fdot2f(u.h[3], w[4 * j4 + 3], a3);
    }
    const float a = (a0 + a1) + (a2 + a3);
    const float v = (sel == 2) ? tanh_f(a) : sigm_f(a);
    gates[sel][h] = v;
    __syncthreads();  // gates ready

    // ---- cell update (first 4 waves) ----
    if (t < HH) {
      const float f_ = gates[0][h], i_ = gates[1][h], g_ = gates[2][h], o_ = gates[3][h];
      cx = fmaf(f_, cx, i_ * g_);
      hxr = o_ * tanh_f(cx);
      out[((size_t)step * BB + b) * HH + h] = hxr;
      hx2[(h >> 6) * 72 + (h & 63)] = (_Float16)hxr;
    }
    __syncthreads();  // hx2 ready for next step
  }

  if (t < HH) {
    const size_t base = (size_t)TT * BB * HH;
    out[base + (size_t)b * HH + h] = hxr;
    out[base + (size_t)BB * HH + (size_t)b * HH + h] = cx;
  }
}

extern "C" void kernel_launch(void* const* d_in, const int* in_sizes, int n_in,
                              void* d_out, int out_size, void* d_ws, size_t ws_size,
                              hipStream_t stream) {
  const float* x     = (const float*)d_in[0];
  const float* proto = (const float*)d_in[1];
  const float* Wf = (const float*)d_in[2];
  const float* bf = (const float*)d_in[3];
  const float* Wi = (const float*)d_in[4];
  const float* bi = (const float*)d_in[5];
  const float* Wg = (const float*)d_in[6];
  const float* bg = (const float*)d_in[7];
  const float* Wo = (const float*)d_in[8];
  const float* bo = (const float*)d_in[9];
  float* out = (float*)d_out;
  _Float16* sxbuf = (_Float16*)d_ws;  // T*B*P*2 = 32 MB

  sx_kernel<<<512, 256, 0, stream>>>(x, proto, sxbuf);
  rec_kernel<<<BB, 1024, 0, stream>>>(sxbuf, proto, Wf, bf, Wi, bi, Wg, bg, Wo, bo, out);
}

// Round 3
// 1017.171 us; speedup vs baseline: 1.0065x; 1.0065x over previous
//
#include <hip/hip_runtime.h>
#include <hip/hip_bf16.h>

// QLSTM: T=512, B=256, D=128, H=256, P=128, GAMMA=1
// Phase 1 (MFMA GEMM): sx[r,p] = ||x_r||^2 + ||px_p||^2 - 2 x_r.px_p  (full Sx, f16, 32MB ws)
// Phase 2 (sequential, 1 WG of 1024 per batch row):
//   Sh via 8 lanes/prototype (32 dims each) with fused |hx|^2; k=exp(-(Sx+Sh));
//   gates: 1 gate-output/thread, fp16 weights PINNED in VGPRs (asm) + b128 LDS
//   broadcast of k. launch_bounds(1024,2) so the 256-VGPR cap lets the weights
//   stay register-resident (grid is 1 block/CU anyway -> no occupancy loss).

#define TT 512
#define BB 256
#define DD 128
#define HH 256
#define PP 128
#define DHH 384

typedef _Float16 h2 __attribute__((ext_vector_type(2)));
typedef _Float16 h8 __attribute__((ext_vector_type(8)));
typedef float f4v __attribute__((ext_vector_type(4)));

union F4H { float4 f; h2 h[4]; };

__device__ __forceinline__ float fdot2f(h2 a, h2 b, float c) {
#if __has_builtin(__builtin_amdgcn_fdot2)
  return __builtin_amdgcn_fdot2(a, b, c, false);
#else
  return c + (float)a.x * (float)b.x + (float)a.y * (float)b.y;
#endif
}

__device__ __forceinline__ void pin_h2(h2& v) { asm volatile("" : "+v"(v)); }

__device__ __forceinline__ float sigm_f(float x) { return 1.f / (1.f + __expf(-x)); }
__device__ __forceinline__ float tanh_f(float x) { return 1.f - 2.f / (1.f + __expf(2.f * x)); }

// ---------------- Phase 1: Sx via MFMA f16 ----------------
// 512 WGs x 256 threads; each WG does 256 rows (4 tiles of 64), all 128 p.
// LDS rows padded to 136 halves (272B) to spread banks.
__global__ __launch_bounds__(256, 2) void sx_kernel(const float* __restrict__ x,
                                                    const float* __restrict__ proto,
                                                    _Float16* __restrict__ sx) {
  __shared__ __align__(16) _Float16 qlds[PP * 136];   // -2*proto_x, f16
  __shared__ __align__(16) _Float16 xlds[64 * 136];   // x tile, f16
  __shared__ float pnlds[PP];
  __shared__ float xnlds[64];

  const int t = threadIdx.x;
  const int lane = t & 63;
  const int wv = t >> 6;          // wave 0..3 -> m-tile
  const int col = lane & 15;
  const int quad = lane >> 4;
  const int r0 = blockIdx.x * 256;

  // ---- stage q = -2*proto_x (f16) + pnorm ----
  {
    const int p = t >> 1;
    const int hh = t & 1;
    const float* src = proto + p * DHH + hh * 64;
    _Float16* dst = qlds + p * 136 + hh * 64;
    float pn = 0.f;
#pragma unroll
    for (int i = 0; i < 8; ++i) {
      float4 a = *(const float4*)(src + i * 8);
      float4 b = *(const float4*)(src + i * 8 + 4);
      pn = fmaf(a.x, a.x, fmaf(a.y, a.y, fmaf(a.z, a.z, fmaf(a.w, a.w, pn))));
      pn = fmaf(b.x, b.x, fmaf(b.y, b.y, fmaf(b.z, b.z, fmaf(b.w, b.w, pn))));
      h8 v;
      v[0] = (_Float16)(-2.f * a.x); v[1] = (_Float16)(-2.f * a.y);
      v[2] = (_Float16)(-2.f * a.z); v[3] = (_Float16)(-2.f * a.w);
      v[4] = (_Float16)(-2.f * b.x); v[5] = (_Float16)(-2.f * b.y);
      v[6] = (_Float16)(-2.f * b.z); v[7] = (_Float16)(-2.f * b.w);
      *(h8*)(dst + i * 8) = v;
    }
    pn += __shfl_xor(pn, 1);
    if (hh == 0) pnlds[p] = pn;
  }

  // ---- stage x tile 0 ----
  {
    const int m = t >> 2;
    const int q4 = t & 3;
    const float* xs = x + ((size_t)(r0 + m)) * DD + q4 * 32;
    _Float16* xd = xlds + m * 136 + q4 * 32;
    float xn = 0.f;
#pragma unroll
    for (int i = 0; i < 4; ++i) {
      float4 a = *(const float4*)(xs + i * 8);
      float4 b = *(const float4*)(xs + i * 8 + 4);
      xn = fmaf(a.x, a.x, fmaf(a.y, a.y, fmaf(a.z, a.z, fmaf(a.w, a.w, xn))));
      xn = fmaf(b.x, b.x, fmaf(b.y, b.y, fmaf(b.z, b.z, fmaf(b.w, b.w, xn))));
      h8 v;
      v[0] = (_Float16)a.x; v[1] = (_Float16)a.y; v[2] = (_Float16)a.z; v[3] = (_Float16)a.w;
      v[4] = (_Float16)b.x; v[5] = (_Float16)b.y; v[6] = (_Float16)b.z; v[7] = (_Float16)b.w;
      *(h8*)(xd + i * 8) = v;
    }
    xn += __shfl_xor(xn, 1);
    xn += __shfl_xor(xn, 2);
    if (q4 == 0) xnlds[m] = xn;
  }
  __syncthreads();

  float pn8[8];
#pragma unroll
  for (int nt = 0; nt < 8; ++nt) pn8[nt] = pnlds[nt * 16 + col];

  for (int tile = 0; tile < 4; ++tile) {
    // ---- compute: wave wv owns 16 rows m0 = wv*16 of this tile ----
    h8 af[4];
#pragma unroll
    for (int kc = 0; kc < 4; ++kc)
      af[kc] = *(const h8*)(xlds + (wv * 16 + col) * 136 + kc * 32 + quad * 8);
    float xnq[4];
#pragma unroll
    for (int r = 0; r < 4; ++r) xnq[r] = xnlds[wv * 16 + quad * 4 + r];

#pragma unroll
    for (int nt = 0; nt < 8; ++nt) {
      f4v acc;
      acc[0] = pn8[nt]; acc[1] = pn8[nt]; acc[2] = pn8[nt]; acc[3] = pn8[nt];
#pragma unroll
      for (int kc = 0; kc < 4; ++kc) {
        h8 bf = *(const h8*)(qlds + (nt * 16 + col) * 136 + kc * 32 + quad * 8);
        acc = __builtin_amdgcn_mfma_f32_16x16x32_f16(af[kc], bf, acc, 0, 0, 0);
      }
#pragma unroll
      for (int r = 0; r < 4; ++r) {
        const int row = r0 + tile * 64 + wv * 16 + quad * 4 + r;
        sx[(size_t)row * PP + nt * 16 + col] = (_Float16)(acc[r] + xnq[r]);
      }
    }

    // ---- stage next x tile ----
    if (tile < 3) {
      __syncthreads();  // compute done before xlds overwrite
      const int m = t >> 2;
      const int q4 = t & 3;
      const float* xs = x + ((size_t)(r0 + (tile + 1) * 64 + m)) * DD + q4 * 32;
      _Float16* xd = xlds + m * 136 + q4 * 32;
      float xn = 0.f;
#pragma unroll
      for (int i = 0; i < 4; ++i) {
        float4 a = *(const float4*)(xs + i * 8);
        float4 b = *(const float4*)(xs + i * 8 + 4);
        xn = fmaf(a.x, a.x, fmaf(a.y, a.y, fmaf(a.z, a.z, fmaf(a.w, a.w, xn))));
        xn = fmaf(b.x, b.x, fmaf(b.y, b.y, fmaf(b.z, b.z, fmaf(b.w, b.w, xn))));
        h8 v;
        v[0] = (_Float16)a.x; v[1] = (_Float16)a.y; v[2] = (_Float16)a.z; v[3] = (_Float16)a.w;
        v[4] = (_Float16)b.x; v[5] = (_Float16)b.y; v[6] = (_Float16)b.z; v[7] = (_Float16)b.w;
        *(h8*)(xd + i * 8) = v;
      }
      xn += __shfl_xor(xn, 1);
      xn += __shfl_xor(xn, 2);
      if (q4 == 0) xnlds[m] = xn;
      __syncthreads();
    }
  }
}

// ---------------- Phase 2: sequential recurrence ----------------
// grid 256 x 1024 threads. launch_bounds(1024,2): VGPR cap 256 so the pinned
// weight registers (64 h2) + proto registers (16 h2) stay resident; occupancy
// is grid-limited to 1 block/CU (16 waves) regardless.
// Sh: 8 threads per prototype (cc=t&7 covers 32 dims each); dot AND |hx|^2
//   both accumulated via fdot2 and reduced in the same 3-stage shuffle.
// Gates: thread t computes gate sel=t>>8 (f,i,g,o) for h=t&255; 64 fdot2,
//   weights in 64 VGPRs, k broadcast from LDS via b128 (uniform addr = free).
// hx in LDS as 4 chunks of 64 halves padded to stride 72 (conflict-free b128).
__global__ __launch_bounds__(1024, 2) void rec_kernel(
    const _Float16* __restrict__ sx, const float* __restrict__ proto,
    const float* __restrict__ Wf, const float* __restrict__ bfv,
    const float* __restrict__ Wi, const float* __restrict__ biv,
    const float* __restrict__ Wg, const float* __restrict__ bgv,
    const float* __restrict__ Wo, const float* __restrict__ bov,
    float* __restrict__ out) {
  const int b = blockIdx.x;
  const int t = threadIdx.x;
  const int h = t & (HH - 1);
  const int sel = t >> 8;  // 0:f 1:i 2:g 3:o  (wave-uniform)

  const float* Wsel = (sel == 0) ? Wf : (sel == 1) ? Wi : (sel == 2) ? Wg : Wo;
  const float* bsel = (sel == 0) ? bfv : (sel == 1) ? biv : (sel == 2) ? bgv : bov;
  const float bias = bsel[h];

  // one gate row of weights, fp16: 64 VGPRs, pinned so the compiler cannot
  // sink the loads/cvts into the 512-step loop (round-2 showed it does).
  h2 w[PP / 2];
#pragma unroll
  for (int j = 0; j < PP / 2; ++j) {
    float2 a = *(const float2*)(Wsel + h * PP + 2 * j);
    h2 u; u.x = (_Float16)a.x; u.y = (_Float16)a.y; w[j] = u;
  }
#pragma unroll
  for (int j = 0; j < PP / 2; ++j) pin_h2(w[j]);

  // prototype h-part: 8 lanes per proto, 32 dims each -> 16 h2 regs, pinned
  const int p = t >> 3;
  const int cc = t & 7;
  h2 ph[16];
  float pnorm = 0.f;
#pragma unroll
  for (int j = 0; j < 16; ++j) {
    float2 a = *(const float2*)(proto + p * DHH + DD + cc * 32 + 2 * j);
    pnorm = fmaf(a.x, a.x, pnorm);
    pnorm = fmaf(a.y, a.y, pnorm);
    h2 u; u.x = (_Float16)(-2.f * a.x); u.y = (_Float16)(-2.f * a.y); ph[j] = u;
  }
#pragma unroll
  for (int j = 0; j < 16; ++j) pin_h2(ph[j]);
  pnorm += __shfl_xor(pnorm, 1);
  pnorm += __shfl_xor(pnorm, 2);
  pnorm += __shfl_xor(pnorm, 4);

  // hx chunks: chunk c holds dims [c*64, c*64+64) at halves [c*72, c*72+64)
  __shared__ __align__(16) _Float16 hx2[4 * 72];
  __shared__ __align__(16) _Float16 kh2[PP];
  __shared__ float gates[4][HH];

  if (t < HH) hx2[(h >> 6) * 72 + (h & 63)] = (_Float16)0.f;
  float cx = 0.f;
  float hxr = 0.f;
  __syncthreads();

  float sx_next = (float)sx[(size_t)b * PP + p];

  const _Float16* hxc = hx2 + (cc >> 1) * 72 + (cc & 1) * 32;

  for (int step = 0; step < TT; ++step) {
    // ---- Sh + |hx|^2 + k ----
    float dA = 0.f, dB = 0.f, sA = 0.f, sB = 0.f;
#pragma unroll
    for (int j4 = 0; j4 < 4; ++j4) {
      F4H u; u.f = *(const float4*)(hxc + j4 * 8);
      dA = fdot2f(u.h[0], ph[4 * j4 + 0], dA);
      sA = fdot2f(u.h[0], u.h[0], sA);
      dB = fdot2f(u.h[1], ph[4 * j4 + 1], dB);
      sB = fdot2f(u.h[1], u.h[1], sB);
      dA = fdot2f(u.h[2], ph[4 * j4 + 2], dA);
      sA = fdot2f(u.h[2], u.h[2], sA);
      dB = fdot2f(u.h[3], ph[4 * j4 + 3], dB);
      sB = fdot2f(u.h[3], u.h[3], sB);
    }
    float dot = dA + dB;
    float sq = sA + sB;
    dot += __shfl_xor(dot, 1); sq += __shfl_xor(sq, 1);
    dot += __shfl_xor(dot, 2); sq += __shfl_xor(sq, 2);
    dot += __shfl_xor(dot, 4); sq += __shfl_xor(sq, 4);

    const float sx_cur = sx_next;
    const int nst = (step + 1 < TT) ? (step + 1) : (TT - 1);
    sx_next = (float)sx[((size_t)nst * BB + b) * PP + p];

    const float d2 = sq + dot + pnorm + sx_cur;
    const float kk = __expf(-d2);
    if (cc == 0) kh2[p] = (_Float16)kk;
    __syncthreads();  // k ready

    // ---- gate: 1 output/thread, b128 k broadcast, 4 acc chains ----
    float a0 = bias, a1 = 0.f, a2 = 0.f, a3 = 0.f;
#pragma unroll
    for (int j4 = 0; j4 < 16; ++j4) {
      F4H u; u.f = *(const float4*)(kh2 + j4 * 8);
      a0 = fdot2f(u.h[0], w[4 * j4 + 0], a0);
      a1 = fdot2f(u.h[1], w[4 * j4 + 1], a1);
      a2 = fdot2f(u.h[2], w[4 * j4 + 2], a2);
      a3 = fdot2f(u.h[3], w[4 * j4 + 3], a3);
    }
    const float a = (a0 + a1) + (a2 + a3);
    const float v = (sel == 2) ? tanh_f(a) : sigm_f(a);
    gates[sel][h] = v;
    __syncthreads();  // gates ready

    // ---- cell update (first 4 waves) ----
    if (t < HH) {
      const float f_ = gates[0][h], i_ = gates[1][h], g_ = gates[2][h], o_ = gates[3][h];
      cx = fmaf(f_, cx, i_ * g_);
      hxr = o_ * tanh_f(cx);
      out[((size_t)step * BB + b) * HH + h] = hxr;
      hx2[(h >> 6) * 72 + (h & 63)] = (_Float16)hxr;
    }
    __syncthreads();  // hx2 ready for next step
  }

  if (t < HH) {
    const size_t base = (size_t)TT * BB * HH;
    out[base + (size_t)b * HH + h] = hxr;
    out[base + (size_t)BB * HH + (size_t)b * HH + h] = cx;
  }
}

extern "C" void kernel_launch(void* const* d_in, const int* in_sizes, int n_in,
                              void* d_out, int out_size, void* d_ws, size_t ws_size,
                              hipStream_t stream) {
  const float* x     = (const float*)d_in[0];
  const float* proto = (const float*)d_in[1];
  const float* Wf = (const float*)d_in[2];
  const float* bf = (const float*)d_in[3];
  const float* Wi = (const float*)d_in[4];
  const float* bi = (const float*)d_in[5];
  const float* Wg = (const float*)d_in[6];
  const float* bg = (const float*)d_in[7];
  const float* Wo = (const float*)d_in[8];
  const float* bo = (const float*)d_in[9];
  float* out = (float*)d_out;
  _Float16* sxbuf = (_Float16*)d_ws;  // T*B*P*2 = 32 MB

  sx_kernel<<<512, 256, 0, stream>>>(x, proto, sxbuf);
  rec_kernel<<<BB, 1024, 0, stream>>>(sxbuf, proto, Wf, bf, Wi, bi, Wg, bg, Wo, bo, out);
}

// Round 4
// 996.327 us; speedup vs baseline: 1.0275x; 1.0209x over previous
//
#include <hip/hip_runtime.h>
#include <hip/hip_bf16.h>

// QLSTM: T=512, B=256, D=128, H=256, P=128, GAMMA=1
// Phase 1 (MFMA GEMM): sx[r,p] = ||x_r||^2 + ||px_p||^2 - 2 x_r.px_p  (full Sx, f16, 32MB ws)
// Phase 2: 256 WGs (1 batch row each) x 512 threads (8 waves, 2/SIMD -> 256 VGPR budget).
//   ALL dot products on the MFMA pipe with M=1 rows inside 16x16x32 f16 tiles:
//     Sh:    [1 x 256] @ (-2*proto_h^T)[256 x 128]  -> 8 p-tiles, wave w owns tile w (8 chained MFMA)
//     gates: [1 x 128] @ W^T[128 x 1024]            -> wave w owns h in [w*32,w*32+32) for ALL 4 gates
//   Weights/proto live as MFMA B-fragments (AGPR-friendly: MFMA reads AGPR directly,
//   no per-use moves). f,i,g,o for the same h sit in one lane's accs -> in-register
//   cell update; 2 barriers/step. All A-rows are duplicates of row 0, so every lane
//   holds valid (duplicated) values - guarded stores only.

#define TT 512
#define BB 256
#define DD 128
#define HH 256
#define PP 128
#define DHH 384

typedef _Float16 h2 __attribute__((ext_vector_type(2)));
typedef _Float16 h8 __attribute__((ext_vector_type(8)));
typedef float f4v __attribute__((ext_vector_type(4)));

__device__ __forceinline__ void pin_h8(h8& v) { asm volatile("" : "+v"(v)); }

__device__ __forceinline__ float sigm_f(float x) { return 1.f / (1.f + __expf(-x)); }
__device__ __forceinline__ float tanh_f(float x) { return 1.f - 2.f / (1.f + __expf(2.f * x)); }

__device__ __forceinline__ h8 pack_h8(float4 a, float4 b2, float s) {
  h8 v;
  v[0] = (_Float16)(s * a.x);  v[1] = (_Float16)(s * a.y);
  v[2] = (_Float16)(s * a.z);  v[3] = (_Float16)(s * a.w);
  v[4] = (_Float16)(s * b2.x); v[5] = (_Float16)(s * b2.y);
  v[6] = (_Float16)(s * b2.z); v[7] = (_Float16)(s * b2.w);
  return v;
}

// ---------------- Phase 1: Sx via MFMA f16 ----------------
// 512 WGs x 256 threads; each WG does 256 rows (4 tiles of 64), all 128 p.
// LDS rows padded to 136 halves (272B) to spread banks.
__global__ __launch_bounds__(256, 2) void sx_kernel(const float* __restrict__ x,
                                                    const float* __restrict__ proto,
                                                    _Float16* __restrict__ sx) {
  __shared__ __align__(16) _Float16 qlds[PP * 136];   // -2*proto_x, f16
  __shared__ __align__(16) _Float16 xlds[64 * 136];   // x tile, f16
  __shared__ float pnlds[PP];
  __shared__ float xnlds[64];

  const int t = threadIdx.x;
  const int lane = t & 63;
  const int wv = t >> 6;          // wave 0..3 -> m-tile
  const int col = lane & 15;
  const int quad = lane >> 4;
  const int r0 = blockIdx.x * 256;

  // ---- stage q = -2*proto_x (f16) + pnorm ----
  {
    const int p = t >> 1;
    const int hh = t & 1;
    const float* src = proto + p * DHH + hh * 64;
    _Float16* dst = qlds + p * 136 + hh * 64;
    float pn = 0.f;
#pragma unroll
    for (int i = 0; i < 8; ++i) {
      float4 a = *(const float4*)(src + i * 8);
      float4 b = *(const float4*)(src + i * 8 + 4);
      pn = fmaf(a.x, a.x, fmaf(a.y, a.y, fmaf(a.z, a.z, fmaf(a.w, a.w, pn))));
      pn = fmaf(b.x, b.x, fmaf(b.y, b.y, fmaf(b.z, b.z, fmaf(b.w, b.w, pn))));
      *(h8*)(dst + i * 8) = pack_h8(a, b, -2.f);
    }
    pn += __shfl_xor(pn, 1);
    if (hh == 0) pnlds[p] = pn;
  }

  // ---- stage x tile 0 ----
  {
    const int m = t >> 2;
    const int q4 = t & 3;
    const float* xs = x + ((size_t)(r0 + m)) * DD + q4 * 32;
    _Float16* xd = xlds + m * 136 + q4 * 32;
    float xn = 0.f;
#pragma unroll
    for (int i = 0; i < 4; ++i) {
      float4 a = *(const float4*)(xs + i * 8);
      float4 b = *(const float4*)(xs + i * 8 + 4);
      xn = fmaf(a.x, a.x, fmaf(a.y, a.y, fmaf(a.z, a.z, fmaf(a.w, a.w, xn))));
      xn = fmaf(b.x, b.x, fmaf(b.y, b.y, fmaf(b.z, b.z, fmaf(b.w, b.w, xn))));
      *(h8*)(xd + i * 8) = pack_h8(a, b, 1.f);
    }
    xn += __shfl_xor(xn, 1);
    xn += __shfl_xor(xn, 2);
    if (q4 == 0) xnlds[m] = xn;
  }
  __syncthreads();

  float pn8[8];
#pragma unroll
  for (int nt = 0; nt < 8; ++nt) pn8[nt] = pnlds[nt * 16 + col];

  for (int tile = 0; tile < 4; ++tile) {
    h8 af[4];
#pragma unroll
    for (int kc = 0; kc < 4; ++kc)
      af[kc] = *(const h8*)(xlds + (wv * 16 + col) * 136 + kc * 32 + quad * 8);
    float xnq[4];
#pragma unroll
    for (int r = 0; r < 4; ++r) xnq[r] = xnlds[wv * 16 + quad * 4 + r];

#pragma unroll
    for (int nt = 0; nt < 8; ++nt) {
      f4v acc;
      acc[0] = pn8[nt]; acc[1] = pn8[nt]; acc[2] = pn8[nt]; acc[3] = pn8[nt];
#pragma unroll
      for (int kc = 0; kc < 4; ++kc) {
        h8 bf = *(const h8*)(qlds + (nt * 16 + col) * 136 + kc * 32 + quad * 8);
        acc = __builtin_amdgcn_mfma_f32_16x16x32_f16(af[kc], bf, acc, 0, 0, 0);
      }
#pragma unroll
      for (int r = 0; r < 4; ++r) {
        const int row = r0 + tile * 64 + wv * 16 + quad * 4 + r;
        sx[(size_t)row * PP + nt * 16 + col] = (_Float16)(acc[r] + xnq[r]);
      }
    }

    if (tile < 3) {
      __syncthreads();
      const int m = t >> 2;
      const int q4 = t & 3;
      const float* xs = x + ((size_t)(r0 + (tile + 1) * 64 + m)) * DD + q4 * 32;
      _Float16* xd = xlds + m * 136 + q4 * 32;
      float xn = 0.f;
#pragma unroll
      for (int i = 0; i < 4; ++i) {
        float4 a = *(const float4*)(xs + i * 8);
        float4 b = *(const float4*)(xs + i * 8 + 4);
        xn = fmaf(a.x, a.x, fmaf(a.y, a.y, fmaf(a.z, a.z, fmaf(a.w, a.w, xn))));
        xn = fmaf(b.x, b.x, fmaf(b.y, b.y, fmaf(b.z, b.z, fmaf(b.w, b.w, xn))));
        *(h8*)(xd + i * 8) = pack_h8(a, b, 1.f);
      }
      xn += __shfl_xor(xn, 1);
      xn += __shfl_xor(xn, 2);
      if (q4 == 0) xnlds[m] = xn;
      __syncthreads();
    }
  }
}

// ---------------- Phase 2: sequential recurrence (MFMA GEMV) ----------------
__global__ __launch_bounds__(512, 2) void rec_kernel(
    const _Float16* __restrict__ sx, const float* __restrict__ proto,
    const float* __restrict__ Wf, const float* __restrict__ bfv,
    const float* __restrict__ Wi, const float* __restrict__ biv,
    const float* __restrict__ Wg, const float* __restrict__ bgv,
    const float* __restrict__ Wo, const float* __restrict__ bov,
    float* __restrict__ out) {
  const int b = blockIdx.x;
  const int t = threadIdx.x;
  const int w = t >> 6;     // wave 0..7
  const int l = t & 63;
  const int lc = l & 15;    // B-frag column / C column
  const int lg = l >> 4;    // k-group 0..3 (8 contiguous k elems each)

  const float* const Warr[4] = {Wf, Wi, Wg, Wo};
  const float* const barr[4] = {bfv, biv, bgv, bov};

  // ---- gate B-frags: tile (g, st): B[k=p][col=h], h = w*32 + st*16 + lc ----
  // lane supplies W_g[h][p = c*32 + lg*8 .. +8]  (8 consecutive p -> 2 float4)
  h8 wfrag[4][2][4];
  float bias[4][2];
#pragma unroll
  for (int g = 0; g < 4; ++g) {
#pragma unroll
    for (int st = 0; st < 2; ++st) {
      const int h = w * 32 + st * 16 + lc;
      const float* row = Warr[g] + (size_t)h * PP;
      bias[g][st] = barr[g][h];
#pragma unroll
      for (int c = 0; c < 4; ++c) {
        float4 a = *(const float4*)(row + c * 32 + lg * 8);
        float4 b2 = *(const float4*)(row + c * 32 + lg * 8 + 4);
        wfrag[g][st][c] = pack_h8(a, b2, 1.f);
      }
    }
  }
#pragma unroll
  for (int g = 0; g < 4; ++g)
#pragma unroll
    for (int st = 0; st < 2; ++st)
#pragma unroll
      for (int c = 0; c < 4; ++c) pin_h8(wfrag[g][st][c]);

  // ---- Sh B-frags (-2 * proto_h^T): tile w covers p = w*16 + lc ----
  // lane supplies (-2*proto[p])[hdim = c*32 + lg*8 .. +8]; pnorm folded in (f32).
  const int p = w * 16 + lc;
  h8 qfrag[8];
  float pn = 0.f;
#pragma unroll
  for (int c = 0; c < 8; ++c) {
    const float* src = proto + (size_t)p * DHH + DD + c * 32 + lg * 8;
    float4 a = *(const float4*)(src);
    float4 b2 = *(const float4*)(src + 4);
    pn = fmaf(a.x, a.x, fmaf(a.y, a.y, fmaf(a.z, a.z, fmaf(a.w, a.w, pn))));
    pn = fmaf(b2.x, b2.x, fmaf(b2.y, b2.y, fmaf(b2.z, b2.z, fmaf(b2.w, b2.w, pn))));
    qfrag[c] = pack_h8(a, b2, -2.f);
  }
#pragma unroll
  for (int c = 0; c < 8; ++c) pin_h8(qfrag[c]);
  pn += __shfl_xor(pn, 16);   // sum over the 4 lg groups (same p)
  pn += __shfl_xor(pn, 32);

  __shared__ __align__(16) _Float16 hxlds[HH];  // hx, f16
  __shared__ __align__(16) _Float16 klds[PP];   // k, f16
  __shared__ __align__(16) float hpart[8];      // per-wave |hx|^2 partials

  if (t < HH) hxlds[t] = (_Float16)0.f;
  if (t < 8) hpart[t] = 0.f;
  float cx0 = 0.f, cx1 = 0.f, hx0 = 0.f, hx1 = 0.f;
  __syncthreads();

  float sx_next = (float)sx[(size_t)b * PP + p];

  const f4v zacc = {0.f, 0.f, 0.f, 0.f};

  for (int step = 0; step < TT; ++step) {
    // ---- Sh: d2 = |hx|^2 + (-2 hx.ph) + |ph|^2 + sx ; k = exp(-d2) ----
    float4 hp0 = *(const float4*)(hpart);
    float4 hp1 = *(const float4*)(hpart + 4);
    const float hsq = ((hp0.x + hp0.y) + (hp0.z + hp0.w)) +
                      ((hp1.x + hp1.y) + (hp1.z + hp1.w));

    f4v accA = zacc, accB = zacc;
#pragma unroll
    for (int c = 0; c < 4; ++c) {
      h8 af = *(const h8*)(hxlds + c * 32 + lg * 8);
      accA = __builtin_amdgcn_mfma_f32_16x16x32_f16(af, qfrag[c], accA, 0, 0, 0);
    }
#pragma unroll
    for (int c = 4; c < 8; ++c) {
      h8 af = *(const h8*)(hxlds + c * 32 + lg * 8);
      accB = __builtin_amdgcn_mfma_f32_16x16x32_f16(af, qfrag[c], accB, 0, 0, 0);
    }

    const float sx_cur = sx_next;
    const int nst = (step + 1 < TT) ? (step + 1) : (TT - 1);
    sx_next = (float)sx[((size_t)nst * BB + b) * PP + p];

    const float d2 = (accA[0] + accB[0]) + hsq + pn + sx_cur;
    const float kk = __expf(-d2);
    if (l < 16) klds[p] = (_Float16)kk;
    __syncthreads();  // k ready

    // ---- gates: 4 gates x 2 subtiles, K=128 (4 chained MFMA each) ----
    f4v acc[4][2];
#pragma unroll
    for (int g = 0; g < 4; ++g)
#pragma unroll
      for (int st = 0; st < 2; ++st) acc[g][st] = zacc;
#pragma unroll
    for (int c = 0; c < 4; ++c) {
      h8 kf = *(const h8*)(klds + c * 32 + lg * 8);
#pragma unroll
      for (int g = 0; g < 4; ++g) {
#pragma unroll
        for (int st = 0; st < 2; ++st)
          acc[g][st] = __builtin_amdgcn_mfma_f32_16x16x32_f16(kf, wfrag[g][st][c],
                                                              acc[g][st], 0, 0, 0);
      }
    }

    // ---- activations + in-register cell update (all lanes hold valid dups) ----
    const float f0 = sigm_f(acc[0][0][0] + bias[0][0]);
    const float i0 = sigm_f(acc[1][0][0] + bias[1][0]);
    const float g0 = tanh_f(acc[2][0][0] + bias[2][0]);
    const float o0 = sigm_f(acc[3][0][0] + bias[3][0]);
    const float f1 = sigm_f(acc[0][1][0] + bias[0][1]);
    const float i1 = sigm_f(acc[1][1][0] + bias[1][1]);
    const float g1 = tanh_f(acc[2][1][0] + bias[2][1]);
    const float o1 = sigm_f(acc[3][1][0] + bias[3][1]);

    cx0 = fmaf(f0, cx0, i0 * g0);
    cx1 = fmaf(f1, cx1, i1 * g1);
    hx0 = o0 * tanh_f(cx0);
    hx1 = o1 * tanh_f(cx1);

    const int h0 = w * 32 + lc;
    if (l < 16) {
      out[((size_t)step * BB + b) * HH + h0] = hx0;
      out[((size_t)step * BB + b) * HH + h0 + 16] = hx1;
      hxlds[h0] = (_Float16)hx0;
      hxlds[h0 + 16] = (_Float16)hx1;
    }
    float sq = fmaf(hx0, hx0, hx1 * hx1);
    sq += __shfl_xor(sq, 1);
    sq += __shfl_xor(sq, 2);
    sq += __shfl_xor(sq, 4);
    sq += __shfl_xor(sq, 8);
    if (l == 0) hpart[w] = sq;
    __syncthreads();  // hx/hpart ready for next step
  }

  if (l < 16) {
    const int h0 = w * 32 + lc;
    const size_t base = (size_t)TT * BB * HH;
    out[base + (size_t)b * HH + h0] = hx0;
    out[base + (size_t)b * HH + h0 + 16] = hx1;
    out[base + (size_t)BB * HH + (size_t)b * HH + h0] = cx0;
    out[base + (size_t)BB * HH + (size_t)b * HH + h0 + 16] = cx1;
  }
}

extern "C" void kernel_launch(void* const* d_in, const int* in_sizes, int n_in,
                              void* d_out, int out_size, void* d_ws, size_t ws_size,
                              hipStream_t stream) {
  const float* x     = (const float*)d_in[0];
  const float* proto = (const float*)d_in[1];
  const float* Wf = (const float*)d_in[2];
  const float* bf = (const float*)d_in[3];
  const float* Wi = (const float*)d_in[4];
  const float* bi = (const float*)d_in[5];
  const float* Wg = (const float*)d_in[6];
  const float* bg = (const float*)d_in[7];
  const float* Wo = (const float*)d_in[8];
  const float* bo = (const float*)d_in[9];
  float* out = (float*)d_out;
  _Float16* sxbuf = (_Float16*)d_ws;  // T*B*P*2 = 32 MB

  sx_kernel<<<512, 256, 0, stream>>>(x, proto, sxbuf);
  rec_kernel<<<BB, 512, 0, stream>>>(sxbuf, proto, Wf, bf, Wi, bi, Wg, bg, Wo, bo, out);
}